// Round 5
// baseline (163.306 us; speedup 1.0000x reference)
//
#include <hip/hip_runtime.h>
#include <stdint.h>

#define S_INV (1.0f / 7.0f)
#define COORD_W 5.0f
#define NOOBJ_W 0.5f

// T14 structure: per-wave reg-prefetch (15 x float4 = 60 VGPR) + single
// 15360-B LDS slice. 8 waves/block (512 thr) -> 2 waves/SIMD; counted
// pipelining comes from issuing next chunk's global loads a full compute
// phase before their ds_write consumes them (compiler auto-vmcnt).
// Work split: each wave owns a CONTIGUOUS 784-cell range = 12 x 64-cell
// pipelined chunks + 16-cell direct-load tail (no inter-wave imbalance).
#define WAVES_PER_BLOCK 8
#define SLICE_FLOATS 3840      // 15360 B per wave
#define CHUNK_CELLS 64
#define CHUNK_BYTES (CHUNK_CELLS * 120)   // 15360

__device__ __forceinline__ void cell_loss(const float* ov, const float* tv,
                                          float& acc_total, float& acc_iou,
                                          float& acc_acc)
{
    float w_obj = (tv[4] > 0.f) ? 1.f : 0.f;
    float w_no = 1.f - w_obj;

    // class loss + argmax accuracy (first-max tie-break)
    float cls = 0.f;
    float omax = ov[10]; int oarg = 0;
    float tmax = tv[10]; int targ = 0;
#pragma unroll
    for (int c = 0; c < 20; ++c) {
        float d = ov[10 + c] - tv[10 + c];
        cls += d * d;
        if (ov[10 + c] > omax) { omax = ov[10 + c]; oarg = c; }
        if (tv[10 + c] > tmax) { tmax = tv[10 + c]; targ = c; }
    }

    // IOU of both predicted boxes vs target box 0
    float t_x = tv[0] * S_INV, t_y = tv[1] * S_INV;
    float t_w = tv[2], t_h = tv[3];
    float t_l = t_x - 0.5f * t_w, t_r = t_x + 0.5f * t_w;
    float t_t = t_y - 0.5f * t_h, t_b = t_y + 0.5f * t_h;
    float area_t = t_w * t_h;

    float iou0, iou1;
    {
        float x = ov[0] * S_INV, y = ov[1] * S_INV;
        float w = ov[2], h = ov[3];
        float l = x - 0.5f * w, r = x + 0.5f * w;
        float tt = y - 0.5f * h, bb = y + 0.5f * h;
        float iw = fmaxf(fminf(r, t_r) - fmaxf(l, t_l), 0.f);
        float ih = fmaxf(fminf(bb, t_b) - fmaxf(tt, t_t), 0.f);
        float inter = iw * ih;
        iou0 = inter / (w * h + area_t - inter);
    }
    {
        float x = ov[5] * S_INV, y = ov[6] * S_INV;
        float w = ov[7], h = ov[8];
        float l = x - 0.5f * w, r = x + 0.5f * w;
        float tt = y - 0.5f * h, bb = y + 0.5f * h;
        float iw = fmaxf(fminf(r, t_r) - fmaxf(l, t_l), 0.f);
        float ih = fmaxf(fminf(bb, t_b) - fmaxf(tt, t_t), 0.f);
        float inter = iw * ih;
        iou1 = inter / (w * h + area_t - inter);
    }

    bool r1 = (iou1 > iou0);
    float max_iou = r1 ? iou1 : iou0;

    float os0 = r1 ? ov[5] : ov[0];
    float os1 = r1 ? ov[6] : ov[1];
    float os2 = r1 ? ov[7] : ov[2];
    float os3 = r1 ? ov[8] : ov[3];
    float os4 = r1 ? ov[9] : ov[4];
    float ts0 = r1 ? tv[5] : tv[0];
    float ts1 = r1 ? tv[6] : tv[1];
    float ts2 = r1 ? tv[7] : tv[2];
    float ts3 = r1 ? tv[8] : tv[3];
    float oa4 = r1 ? ov[4] : ov[9];

    float d0 = os0 - ts0, d1 = os1 - ts1;
    float d2 = sqrtf(os2) - sqrtf(ts2);
    float d3 = sqrtf(os3) - sqrtf(ts3);
    float coord = d0 * d0 + d1 * d1 + d2 * d2 + d3 * d3;

    float dc = os4 - max_iou;
    float conf = dc * dc;
    float aband = oa4 * oa4;
    float n0 = ov[4] - tv[4], n1 = ov[9] - tv[9];
    float noobj = n0 * n0 + n1 * n1;

    acc_total += w_obj * (COORD_W * coord + conf + NOOBJ_W * aband + cls)
               + NOOBJ_W * w_no * noobj;
    acc_iou   += w_obj * max_iou;
    acc_acc   += w_obj * ((oarg == targ) ? 1.f : 0.f);
}

__global__ __launch_bounds__(512) void yolo_loss_kernel(
    const float* __restrict__ outp, const float* __restrict__ tgtp,
    float* __restrict__ ws, int cells_per_wave, int nwaves)
{
    __shared__ float lds[WAVES_PER_BLOCK * SLICE_FLOATS];   // 122880 B

    const int wave = threadIdx.x >> 6;
    const int lane = threadIdx.x & 63;
    const int gwave = blockIdx.x * WAVES_PER_BLOCK + wave;

    float* slice = lds + wave * SLICE_FLOATS;
    const size_t wbase = (size_t)gwave * cells_per_wave * 120;   // byte base

    const int nmain = cells_per_wave / CHUNK_CELLS;              // 12
    const int ntail = cells_per_wave - nmain * CHUNK_CELLS;      // 16

    float acc_total = 0.f, acc_iou = 0.f, acc_acc = 0.f;

    float4 pre[15];
    // prologue: load + write chunk 0
#pragma unroll
    for (int j = 0; j < 15; ++j) {
        const int off = j * 1024 + lane * 16;
        const char* src = (off < 7680)
            ? (const char*)outp + wbase + off
            : (const char*)tgtp + wbase + (off - 7680);
        pre[j] = *reinterpret_cast<const float4*>(src);
    }
#pragma unroll
    for (int j = 0; j < 15; ++j)
        *reinterpret_cast<float4*>((char*)slice + j * 1024 + lane * 16) = pre[j];

    float ov[30], tv[30];

#pragma unroll 1
    for (int c = 0; c < nmain; ++c) {
        // 1. issue next chunk's global loads first (long pole)
        const bool has_next = (c + 1) < nmain;
        if (has_next) {
            const size_t cb = wbase + (size_t)(c + 1) * CHUNK_BYTES;
#pragma unroll
            for (int j = 0; j < 15; ++j) {
                const int off = j * 1024 + lane * 16;
                const char* src = (off < 7680)
                    ? (const char*)outp + cb + off
                    : (const char*)tgtp + cb + (off - 7680);
                pre[j] = *reinterpret_cast<const float4*>(src);
            }
        }

        // 2. read own cell from LDS (linear layout; benign 4-way alias)
        const float* oc = slice + lane * 30;
        const float* tc = slice + 1920 + lane * 30;
#pragma unroll
        for (int i = 0; i < 15; ++i) {
            float2 a = *reinterpret_cast<const float2*>(oc + 2 * i);
            float2 b = *reinterpret_cast<const float2*>(tc + 2 * i);
            ov[2 * i] = a.x; ov[2 * i + 1] = a.y;
            tv[2 * i] = b.x; tv[2 * i + 1] = b.y;
        }

        // 3. pin loads/reads above, compute below
        __builtin_amdgcn_sched_barrier(0);

        // 4. compute (hides the prefetch latency)
        cell_loss(ov, tv, acc_total, acc_iou, acc_acc);

        // 5. write next chunk into the (now fully read) slice.
        //    compiler inserts vmcnt waits for pre[]; DS pipe is in-order
        //    per wave so writes land after this iteration's reads.
        if (has_next) {
#pragma unroll
            for (int j = 0; j < 15; ++j)
                *reinterpret_cast<float4*>((char*)slice + j * 1024 + lane * 16) = pre[j];
        }
    }

    // ---- 16-cell tail: direct loads, lanes 0..ntail-1 only ----
    if (lane < ntail) {
        const char* oc = (const char*)outp + wbase + (size_t)(nmain * CHUNK_CELLS + lane) * 120;
        const char* tc = (const char*)tgtp + wbase + (size_t)(nmain * CHUNK_CELLS + lane) * 120;
#pragma unroll
        for (int i = 0; i < 15; ++i) {
            float2 a = *reinterpret_cast<const float2*>(oc + 8 * i);
            float2 b = *reinterpret_cast<const float2*>(tc + 8 * i);
            ov[2 * i] = a.x; ov[2 * i + 1] = a.y;
            tv[2 * i] = b.x; tv[2 * i + 1] = b.y;
        }
        cell_loss(ov, tv, acc_total, acc_iou, acc_acc);
    }

    // ---- wave-local reduction; lane 0 writes SoA partials (no barriers) ----
#pragma unroll
    for (int off = 32; off > 0; off >>= 1) {
        acc_total += __shfl_down(acc_total, off);
        acc_iou   += __shfl_down(acc_iou, off);
        acc_acc   += __shfl_down(acc_acc, off);
    }
    if (lane == 0) {
        ws[gwave]              = acc_total;
        ws[nwaves + gwave]     = acc_iou;
        ws[2 * nwaves + gwave] = acc_acc;
    }
}

__global__ __launch_bounds__(256) void yolo_reduce_kernel(
    const float* __restrict__ ws, float* __restrict__ out, int nwaves)
{
    float t0 = 0.f, t1 = 0.f, t2 = 0.f;
    for (int i = threadIdx.x; i < nwaves; i += blockDim.x) {
        t0 += ws[i];
        t1 += ws[nwaves + i];
        t2 += ws[2 * nwaves + i];
    }
#pragma unroll
    for (int off = 32; off > 0; off >>= 1) {
        t0 += __shfl_down(t0, off);
        t1 += __shfl_down(t1, off);
        t2 += __shfl_down(t2, off);
    }
    __shared__ float s[3][4];
    int wave = threadIdx.x >> 6;
    int lane = threadIdx.x & 63;
    if (lane == 0) { s[0][wave] = t0; s[1][wave] = t1; s[2][wave] = t2; }
    __syncthreads();
    if (threadIdx.x == 0) {
        float a0 = 0.f, a1 = 0.f, a2 = 0.f;
#pragma unroll
        for (int w = 0; w < 4; ++w) { a0 += s[0][w]; a1 += s[1][w]; a2 += s[2][w]; }
        out[0] = a0;   // total
        out[1] = a1;   // sum_iou
        out[2] = a2;   // accurate_num
    }
}

extern "C" void kernel_launch(void* const* d_in, const int* in_sizes, int n_in,
                              void* d_out, int out_size, void* d_ws, size_t ws_size,
                              hipStream_t stream) {
    const float* outp = (const float*)d_in[0];
    const float* tgtp = (const float*)d_in[1];
    float* ws = (float*)d_ws;
    float* o = (float*)d_out;

    const int ncells = in_sizes[0] / 30;            // 32768*7*7 = 1,605,632
    const int blocks = 256;                         // persistent: 1 block/CU
    const int nwaves = blocks * WAVES_PER_BLOCK;    // 2048
    const int cells_per_wave = ncells / nwaves;     // 784 (exact)

    yolo_loss_kernel<<<blocks, 512, 0, stream>>>(outp, tgtp, ws, cells_per_wave, nwaves);
    yolo_reduce_kernel<<<1, 256, 0, stream>>>(ws, o, nwaves);
}

// Round 6
// 116.022 us; speedup vs baseline: 1.4075x; 1.4075x over previous
//
#include <hip/hip_runtime.h>
#include <stdint.h>

#define S_INV (1.0f / 7.0f)
#define COORD_W 5.0f
#define NOOBJ_W 0.5f

// Round-4 proven structure: per-wave double-buffered 64-cell micro-chunks,
// staged via global_load_lds (width 16), counted s_waitcnt vmcnt(15) in the
// steady state (T3/T4: never drain to 0). 256 blocks (1/CU) x 4 waves.
// NEW: final reduction fused into this kernel via last-block-done pattern
// (fixed-order sum -> bit-deterministic), eliminating the 2nd launch.
// Slice layout (bytes): [0,7680) = 64 'out' cells, [7680,15360) = 64 'tgt'.
#define SLICE_FLOATS 3840          // 15360 B per buffer
#define WAVES_PER_BLOCK 4
#define PARTIAL_BASE 64            // floats; counter lives at ws[0]

typedef const __attribute__((address_space(1))) void* gp1_t;
typedef __attribute__((address_space(3))) void* lp3_t;

__device__ __forceinline__ void stage_chunk(const float* __restrict__ outp,
                                            const float* __restrict__ tgtp,
                                            float* dst, int m, int lane)
{
    const size_t cb = (size_t)m * (64 * 120);   // chunk byte offset
#pragma unroll
    for (int j = 0; j < 15; ++j) {
        const int off = j * 1024 + lane * 16;   // linear byte within slice
        const char* src = (off < 7680)
            ? (const char*)outp + cb + off
            : (const char*)tgtp + cb + (off - 7680);
        // LDS dest is wave-uniform base + lane*16 (HW adds lane offset).
        __builtin_amdgcn_global_load_lds((gp1_t)src, (lp3_t)(dst + j * 256),
                                         16, 0, 0);
    }
}

__global__ __launch_bounds__(256) void yolo_loss_kernel(
    const float* __restrict__ outp, const float* __restrict__ tgtp,
    float* __restrict__ ws, float* __restrict__ out,
    int nchunks, int nwaves)
{
    __shared__ float lds[WAVES_PER_BLOCK * 2 * SLICE_FLOATS];   // 122880 B

    const int wave = threadIdx.x >> 6;
    const int lane = threadIdx.x & 63;
    const int gwave = blockIdx.x * WAVES_PER_BLOCK + wave;

    float* bufA = lds + wave * 2 * SLICE_FLOATS;
    float* bufB = bufA + SLICE_FLOATS;
    float* partials = ws + PARTIAL_BASE;

    float acc_total = 0.f, acc_iou = 0.f, acc_acc = 0.f;

    if (gwave < nchunks) stage_chunk(outp, tgtp, bufA, gwave, lane);
    int cur = 0;

    for (int m = gwave; m < nchunks; m += nwaves) {
        const bool has_next = (m + nwaves) < nchunks;   // wave-uniform
        float* bnext = cur ? bufA : bufB;
        float* bcur  = cur ? bufB : bufA;

        if (has_next) {
            stage_chunk(outp, tgtp, bnext, m + nwaves, lane);
            // outstanding = 30; wait to 15 -> current buffer complete,
            // next buffer's 15 loads stay in flight across the compute.
            asm volatile("s_waitcnt vmcnt(15)" ::: "memory");
        } else {
            asm volatile("s_waitcnt vmcnt(0)" ::: "memory");
        }
        __builtin_amdgcn_sched_barrier(0);   // rule #18: no reads above the wait

        // ---- read own cell (linear layout; benign 4-way bank alias) ----
        const float* oc = bcur + lane * 30;
        const float* tc = bcur + 1920 + lane * 30;
        float ov[30], tv[30];
#pragma unroll
        for (int i = 0; i < 15; ++i) {
            float2 a = *reinterpret_cast<const float2*>(oc + 2 * i);
            float2 b = *reinterpret_cast<const float2*>(tc + 2 * i);
            ov[2 * i] = a.x; ov[2 * i + 1] = a.y;
            tv[2 * i] = b.x; tv[2 * i + 1] = b.y;
        }

        float w_obj = (tv[4] > 0.f) ? 1.f : 0.f;
        float w_no = 1.f - w_obj;

        // class loss + argmax accuracy (first-max tie-break)
        float cls = 0.f;
        float omax = ov[10]; int oarg = 0;
        float tmax = tv[10]; int targ = 0;
#pragma unroll
        for (int c = 0; c < 20; ++c) {
            float d = ov[10 + c] - tv[10 + c];
            cls += d * d;
            if (ov[10 + c] > omax) { omax = ov[10 + c]; oarg = c; }
            if (tv[10 + c] > tmax) { tmax = tv[10 + c]; targ = c; }
        }

        // IOU of both predicted boxes vs target box 0
        float t_x = tv[0] * S_INV, t_y = tv[1] * S_INV;
        float t_w = tv[2], t_h = tv[3];
        float t_l = t_x - 0.5f * t_w, t_r = t_x + 0.5f * t_w;
        float t_t = t_y - 0.5f * t_h, t_b = t_y + 0.5f * t_h;
        float area_t = t_w * t_h;

        float iou0, iou1;
        {
            float x = ov[0] * S_INV, y = ov[1] * S_INV;
            float w = ov[2], h = ov[3];
            float l = x - 0.5f * w, r = x + 0.5f * w;
            float tt = y - 0.5f * h, bb = y + 0.5f * h;
            float iw = fmaxf(fminf(r, t_r) - fmaxf(l, t_l), 0.f);
            float ih = fmaxf(fminf(bb, t_b) - fmaxf(tt, t_t), 0.f);
            float inter = iw * ih;
            iou0 = inter / (w * h + area_t - inter);
        }
        {
            float x = ov[5] * S_INV, y = ov[6] * S_INV;
            float w = ov[7], h = ov[8];
            float l = x - 0.5f * w, r = x + 0.5f * w;
            float tt = y - 0.5f * h, bb = y + 0.5f * h;
            float iw = fmaxf(fminf(r, t_r) - fmaxf(l, t_l), 0.f);
            float ih = fmaxf(fminf(bb, t_b) - fmaxf(tt, t_t), 0.f);
            float inter = iw * ih;
            iou1 = inter / (w * h + area_t - inter);
        }

        bool r1 = (iou1 > iou0);
        float max_iou = r1 ? iou1 : iou0;

        float os0 = r1 ? ov[5] : ov[0];
        float os1 = r1 ? ov[6] : ov[1];
        float os2 = r1 ? ov[7] : ov[2];
        float os3 = r1 ? ov[8] : ov[3];
        float os4 = r1 ? ov[9] : ov[4];
        float ts0 = r1 ? tv[5] : tv[0];
        float ts1 = r1 ? tv[6] : tv[1];
        float ts2 = r1 ? tv[7] : tv[2];
        float ts3 = r1 ? tv[8] : tv[3];
        float oa4 = r1 ? ov[4] : ov[9];

        float d0 = os0 - ts0, d1 = os1 - ts1;
        float d2 = sqrtf(os2) - sqrtf(ts2);
        float d3 = sqrtf(os3) - sqrtf(ts3);
        float coord = d0 * d0 + d1 * d1 + d2 * d2 + d3 * d3;

        float dc = os4 - max_iou;
        float conf = dc * dc;
        float aband = oa4 * oa4;
        float n0 = ov[4] - tv[4], n1 = ov[9] - tv[9];
        float noobj = n0 * n0 + n1 * n1;

        float cell_total = w_obj * (COORD_W * coord + conf + NOOBJ_W * aband + cls)
                         + NOOBJ_W * w_no * noobj;

        acc_total += cell_total;
        acc_iou   += w_obj * max_iou;
        acc_acc   += w_obj * ((oarg == targ) ? 1.f : 0.f);

        __builtin_amdgcn_sched_barrier(0);   // WAR: next STAGE stays below reads
        cur ^= 1;
    }

    // ---- wave-local reduction; lane 0 publishes SoA partials ----
#pragma unroll
    for (int off = 32; off > 0; off >>= 1) {
        acc_total += __shfl_down(acc_total, off);
        acc_iou   += __shfl_down(acc_iou, off);
        acc_acc   += __shfl_down(acc_acc, off);
    }
    if (lane == 0) {
        partials[gwave]              = acc_total;
        partials[nwaves + gwave]     = acc_iou;
        partials[2 * nwaves + gwave] = acc_acc;
        __threadfence();   // release this wave's partial (device scope)
    }
    __syncthreads();

    // ---- last-block-done final reduction (fixed order -> deterministic) ----
    __shared__ unsigned last_flag;
    if (threadIdx.x == 0) {
        unsigned v = atomicAdd((unsigned*)ws, 1u);   // counter at ws[0]
        last_flag = (v == (unsigned)(gridDim.x - 1)) ? 1u : 0u;
    }
    __syncthreads();
    if (last_flag) {
        __threadfence();   // acquire all blocks' partials
        float t0 = 0.f, t1 = 0.f, t2 = 0.f;
        for (int i = threadIdx.x; i < nwaves; i += 256) {
            t0 += partials[i];
            t1 += partials[nwaves + i];
            t2 += partials[2 * nwaves + i];
        }
#pragma unroll
        for (int off = 32; off > 0; off >>= 1) {
            t0 += __shfl_down(t0, off);
            t1 += __shfl_down(t1, off);
            t2 += __shfl_down(t2, off);
        }
        __shared__ float s[3][4];
        if (lane == 0) { s[0][wave] = t0; s[1][wave] = t1; s[2][wave] = t2; }
        __syncthreads();
        if (threadIdx.x == 0) {
            float a0 = 0.f, a1 = 0.f, a2 = 0.f;
#pragma unroll
            for (int w = 0; w < 4; ++w) { a0 += s[0][w]; a1 += s[1][w]; a2 += s[2][w]; }
            out[0] = a0;   // total
            out[1] = a1;   // sum_iou
            out[2] = a2;   // accurate_num
        }
    }
}

extern "C" void kernel_launch(void* const* d_in, const int* in_sizes, int n_in,
                              void* d_out, int out_size, void* d_ws, size_t ws_size,
                              hipStream_t stream) {
    const float* outp = (const float*)d_in[0];
    const float* tgtp = (const float*)d_in[1];
    float* ws = (float*)d_ws;
    float* o = (float*)d_out;

    const int ncells  = in_sizes[0] / 30;           // 32768*7*7 = 1,605,632
    const int nchunks = ncells / 64;                // 25,088 (exact)
    const int blocks  = 256;                        // persistent: 1 block/CU
    const int nwaves  = blocks * WAVES_PER_BLOCK;   // 1024

    // zero the last-block counter (ws[0]) -- graph-capturable async memset
    hipMemsetAsync(ws, 0, sizeof(unsigned), stream);

    yolo_loss_kernel<<<blocks, 256, 0, stream>>>(outp, tgtp, ws, o, nchunks, nwaves);
}

// Round 8
// 79.242 us; speedup vs baseline: 2.0608x; 1.4641x over previous
//
#include <hip/hip_runtime.h>
#include <stdint.h>

#define S_INV (1.0f / 7.0f)
#define COORD_W 5.0f
#define NOOBJ_W 0.5f

// Round-8 structure: 1-wave workgroups (64 thr), per-wave double-buffered
// 32-cell micro-chunks. Combined linear buffer of 7680 B per chunk
// ([0,3840) = 32 'out' cells, [3840,7680) = 32 'tgt' cells), staged via
// global_load_lds using ONLY HW-verified widths: 7 x 16B + 2 x 4B = 7680 B
// exactly (width 12 is NOT verified and produced NaN in round 7).
// Counted s_waitcnt vmcnt(9) steady state (T3/T4: never drain mid-loop).
// LDS/block = 15360 B -> 10 blocks/CU = 10 waves/CU (2.5x round-4),
// in-flight ~77 KB/CU, injection spread across 10 independent waves.
// Compute on lanes 0..31 (cell == lane); lanes 32-63 reduce zeros.
#define CHUNK_CELLS 32
#define BUF_FLOATS 1920                    // 7680 B per buffer
#define CHUNK_BYTES (CHUNK_CELLS * 120)    // 3840 B per array-part

typedef const __attribute__((address_space(1))) void* gp1_t;
typedef __attribute__((address_space(3))) void* lp3_t;

__device__ __forceinline__ void stage_chunk(const float* __restrict__ outp,
                                            const float* __restrict__ tgtp,
                                            float* dst, int m, int lane)
{
    const size_t cb = (size_t)m * CHUNK_BYTES;   // byte offset into each array
    // 7 x 16B loads cover combined [0, 7168)
#pragma unroll
    for (int j = 0; j < 7; ++j) {
        const int off = j * 1024 + lane * 16;    // combined-buffer byte offset
        const char* src = (off < 3840)
            ? (const char*)outp + cb + off
            : (const char*)tgtp + cb + (off - 3840);
        __builtin_amdgcn_global_load_lds((gp1_t)src,
                                         (lp3_t)((char*)dst + j * 1024),
                                         16, 0, 0);
    }
    // 2 x 4B loads cover [7168, 7680) -- entirely in the 'tgt' half
#pragma unroll
    for (int j = 0; j < 2; ++j) {
        const int off = 7168 + j * 256 + lane * 4;
        const char* src = (const char*)tgtp + cb + (off - 3840);
        __builtin_amdgcn_global_load_lds((gp1_t)src,
                                         (lp3_t)((char*)dst + 7168 + j * 256),
                                         4, 0, 0);
    }
}

__global__ __launch_bounds__(64) void yolo_loss_kernel(
    const float* __restrict__ outp, const float* __restrict__ tgtp,
    float* __restrict__ ws, int nchunks, int nwaves)
{
    __shared__ float lds[2 * BUF_FLOATS];   // 15360 B

    const int lane = threadIdx.x;           // 1 wave per block
    const int gwave = blockIdx.x;

    float* bufA = lds;
    float* bufB = lds + BUF_FLOATS;

    float acc_total = 0.f, acc_iou = 0.f, acc_acc = 0.f;

    if (gwave < nchunks) stage_chunk(outp, tgtp, bufA, gwave, lane);
    int cur = 0;

    for (int m = gwave; m < nchunks; m += nwaves) {
        const bool has_next = (m + nwaves) < nchunks;   // wave-uniform
        float* bnext = cur ? bufA : bufB;
        float* bcur  = cur ? bufB : bufA;

        if (has_next) {
            stage_chunk(outp, tgtp, bnext, m + nwaves, lane);
            // outstanding = 18; wait to 9 -> current buffer complete,
            // next buffer's 9 loads stay in flight across compute.
            asm volatile("s_waitcnt vmcnt(9)" ::: "memory");
        } else {
            asm volatile("s_waitcnt vmcnt(0)" ::: "memory");
        }
        __builtin_amdgcn_sched_barrier(0);   // rule #18: no reads above wait

        if (lane < CHUNK_CELLS) {
            // ---- read own cell (2-way bank alias only = free) ----
            const float* oc = bcur + lane * 30;
            const float* tc = bcur + 960 + lane * 30;
            float ov[30], tv[30];
#pragma unroll
            for (int i = 0; i < 15; ++i) {
                float2 a = *reinterpret_cast<const float2*>(oc + 2 * i);
                float2 b = *reinterpret_cast<const float2*>(tc + 2 * i);
                ov[2 * i] = a.x; ov[2 * i + 1] = a.y;
                tv[2 * i] = b.x; tv[2 * i + 1] = b.y;
            }

            float w_obj = (tv[4] > 0.f) ? 1.f : 0.f;
            float w_no = 1.f - w_obj;

            // class loss + argmax accuracy (first-max tie-break)
            float cls = 0.f;
            float omax = ov[10]; int oarg = 0;
            float tmax = tv[10]; int targ = 0;
#pragma unroll
            for (int c = 0; c < 20; ++c) {
                float d = ov[10 + c] - tv[10 + c];
                cls += d * d;
                if (ov[10 + c] > omax) { omax = ov[10 + c]; oarg = c; }
                if (tv[10 + c] > tmax) { tmax = tv[10 + c]; targ = c; }
            }

            // IOU of both predicted boxes vs target box 0
            float t_x = tv[0] * S_INV, t_y = tv[1] * S_INV;
            float t_w = tv[2], t_h = tv[3];
            float t_l = t_x - 0.5f * t_w, t_r = t_x + 0.5f * t_w;
            float t_t = t_y - 0.5f * t_h, t_b = t_y + 0.5f * t_h;
            float area_t = t_w * t_h;

            float iou0, iou1;
            {
                float x = ov[0] * S_INV, y = ov[1] * S_INV;
                float w = ov[2], h = ov[3];
                float l = x - 0.5f * w, r = x + 0.5f * w;
                float tt = y - 0.5f * h, bb = y + 0.5f * h;
                float iw = fmaxf(fminf(r, t_r) - fmaxf(l, t_l), 0.f);
                float ih = fmaxf(fminf(bb, t_b) - fmaxf(tt, t_t), 0.f);
                float inter = iw * ih;
                iou0 = inter / (w * h + area_t - inter);
            }
            {
                float x = ov[5] * S_INV, y = ov[6] * S_INV;
                float w = ov[7], h = ov[8];
                float l = x - 0.5f * w, r = x + 0.5f * w;
                float tt = y - 0.5f * h, bb = y + 0.5f * h;
                float iw = fmaxf(fminf(r, t_r) - fmaxf(l, t_l), 0.f);
                float ih = fmaxf(fminf(bb, t_b) - fmaxf(tt, t_t), 0.f);
                float inter = iw * ih;
                iou1 = inter / (w * h + area_t - inter);
            }

            bool r1 = (iou1 > iou0);
            float max_iou = r1 ? iou1 : iou0;

            float os0 = r1 ? ov[5] : ov[0];
            float os1 = r1 ? ov[6] : ov[1];
            float os2 = r1 ? ov[7] : ov[2];
            float os3 = r1 ? ov[8] : ov[3];
            float os4 = r1 ? ov[9] : ov[4];
            float ts0 = r1 ? tv[5] : tv[0];
            float ts1 = r1 ? tv[6] : tv[1];
            float ts2 = r1 ? tv[7] : tv[2];
            float ts3 = r1 ? tv[8] : tv[3];
            float oa4 = r1 ? ov[4] : ov[9];

            float d0 = os0 - ts0, d1 = os1 - ts1;
            float d2 = sqrtf(os2) - sqrtf(ts2);
            float d3 = sqrtf(os3) - sqrtf(ts3);
            float coord = d0 * d0 + d1 * d1 + d2 * d2 + d3 * d3;

            float dc = os4 - max_iou;
            float conf = dc * dc;
            float aband = oa4 * oa4;
            float n0 = ov[4] - tv[4], n1 = ov[9] - tv[9];
            float noobj = n0 * n0 + n1 * n1;

            acc_total += w_obj * (COORD_W * coord + conf + NOOBJ_W * aband + cls)
                       + NOOBJ_W * w_no * noobj;
            acc_iou   += w_obj * max_iou;
            acc_acc   += w_obj * ((oarg == targ) ? 1.f : 0.f);
        }

        __builtin_amdgcn_sched_barrier(0);   // WAR: next STAGE stays below reads
        cur ^= 1;
    }

    // ---- wave-local reduction (upper lanes hold zeros); lane 0 writes ----
#pragma unroll
    for (int off = 32; off > 0; off >>= 1) {
        acc_total += __shfl_down(acc_total, off);
        acc_iou   += __shfl_down(acc_iou, off);
        acc_acc   += __shfl_down(acc_acc, off);
    }
    if (lane == 0) {
        ws[gwave]              = acc_total;
        ws[nwaves + gwave]     = acc_iou;
        ws[2 * nwaves + gwave] = acc_acc;
    }
}

__global__ __launch_bounds__(256) void yolo_reduce_kernel(
    const float* __restrict__ ws, float* __restrict__ out, int nwaves)
{
    float t0 = 0.f, t1 = 0.f, t2 = 0.f;
    for (int i = threadIdx.x; i < nwaves; i += blockDim.x) {
        t0 += ws[i];
        t1 += ws[nwaves + i];
        t2 += ws[2 * nwaves + i];
    }
#pragma unroll
    for (int off = 32; off > 0; off >>= 1) {
        t0 += __shfl_down(t0, off);
        t1 += __shfl_down(t1, off);
        t2 += __shfl_down(t2, off);
    }
    __shared__ float s[3][4];
    int wave = threadIdx.x >> 6;
    int lane = threadIdx.x & 63;
    if (lane == 0) { s[0][wave] = t0; s[1][wave] = t1; s[2][wave] = t2; }
    __syncthreads();
    if (threadIdx.x == 0) {
        float a0 = 0.f, a1 = 0.f, a2 = 0.f;
#pragma unroll
        for (int w = 0; w < 4; ++w) { a0 += s[0][w]; a1 += s[1][w]; a2 += s[2][w]; }
        out[0] = a0;   // total
        out[1] = a1;   // sum_iou
        out[2] = a2;   // accurate_num
    }
}

extern "C" void kernel_launch(void* const* d_in, const int* in_sizes, int n_in,
                              void* d_out, int out_size, void* d_ws, size_t ws_size,
                              hipStream_t stream) {
    const float* outp = (const float*)d_in[0];
    const float* tgtp = (const float*)d_in[1];
    float* ws = (float*)d_ws;
    float* o = (float*)d_out;

    const int ncells  = in_sizes[0] / 30;        // 32768*7*7 = 1,605,632
    const int nchunks = ncells / CHUNK_CELLS;    // 50,176 (exact)
    const int blocks  = 2560;                    // 10 blocks/CU (LDS-resident)
    const int nwaves  = blocks;                  // 1 wave per block

    yolo_loss_kernel<<<blocks, 64, 0, stream>>>(outp, tgtp, ws, nchunks, nwaves);
    yolo_reduce_kernel<<<1, 256, 0, stream>>>(ws, o, nwaves);
}